// Round 1
// baseline (313.514 us; speedup 1.0000x reference)
//
#include <hip/hip_runtime.h>
#include <stdint.h>

#define NB 8
#define NI 16
#define NC 256
#define SH 512

// workspace layout (bytes)
static const size_t OFF_M0   = 0;                                  // u16 mask words, level0: 8*16384*2
static const size_t OFF_M1   = OFF_M0 + (size_t)NB * 16384 * 2;    // 262144
static const size_t OFF_M2   = OFF_M1 + (size_t)NB * 4096 * 2;     // 327680
static const size_t OFF_CNT  = OFF_M2 + (size_t)NB * 1024 * 2;     // 344064  int[3][8][16]
static const size_t OFF_ARG  = OFF_CNT + (size_t)3 * NB * NI * 4;  // 345600  u64[3][8][16]
static const size_t OFF_SSUM = OFF_ARG + (size_t)3 * NB * NI * 8;  // 348672  f32[3][8][16][256]
static const size_t WS_NEED  = OFF_SSUM + (size_t)3 * NB * NI * NC * 4; // 741888

// ---------------------------------------------------------------------------
// Kernel 1: per level, per pixel: sr for all 16 instances (exact 2x2 average),
// pack 16 mask bits -> ws, ballot-count cnt, wave-reduced argmax key -> atomicMax.
// key = (float_bits(sr) << 32) | (0xFFFFFFFF - pix)  => max value, first index.
// (sr >= 0 always: scribbles are uniform[0,1).)
// ---------------------------------------------------------------------------
template<int W, int S>
__global__ void mask_kernel(const float* __restrict__ scr,
                            uint16_t* __restrict__ mask,
                            int* __restrict__ cnt,
                            unsigned long long* __restrict__ argm) {
    const int P = W * W;
    const int pix = blockIdx.x * 256 + threadIdx.x;
    const int b = blockIdx.y;
    const int y = pix / W;
    const int x = pix - y * W;
    const int r0 = S * y + (S / 2 - 1);
    const int c0 = S * x + (S / 2 - 1);
    const int lane = threadIdx.x & 63;
    const float* sb = scr + (size_t)b * NI * SH * SH + (size_t)r0 * SH + c0;
    unsigned int mword = 0;
    for (int i = 0; i < NI; ++i) {
        const float* sp = sb + (size_t)i * SH * SH;
        float s4 = (sp[0] + sp[1]) + (sp[SH] + sp[SH + 1]);
        float sr = 0.25f * s4;
        bool bit = sr > 0.5f;
        mword |= bit ? (1u << i) : 0u;
        unsigned long long bal = __ballot(bit);
        unsigned long long key = (((unsigned long long)__float_as_uint(sr)) << 32)
                               | (unsigned long long)(0xFFFFFFFFu - (unsigned int)pix);
        #pragma unroll
        for (int off = 32; off > 0; off >>= 1) {
            unsigned long long o = __shfl_down(key, (unsigned)off, 64);
            key = (o > key) ? o : key;
        }
        if (lane == 0) {
            atomicAdd(&cnt[b * NI + i], (int)__popcll(bal));
            atomicMax(&argm[b * NI + i], key);
        }
    }
    mask[(size_t)b * P + pix] = (uint16_t)mword;
}

// ---------------------------------------------------------------------------
// Kernel 2: masked channel sums. thread = channel (256/block), loop pixels in
// float4 steps; mask words staged in LDS (uniform across lanes); 16 register
// accumulators; one atomicAdd per (i, c) per block at the end.
// Reads each feature value exactly once for all 16 instances.
// ---------------------------------------------------------------------------
template<int P, int PT>
__global__ void ssum_kernel(const float* __restrict__ f,
                            const uint16_t* __restrict__ mask,
                            float* __restrict__ ssum) {
    __shared__ __align__(8) uint16_t lm[PT];
    const int b = blockIdx.y;
    const int p0 = blockIdx.x * PT;
    const int tid = threadIdx.x;
    for (int j = tid; j < PT; j += 256) lm[j] = mask[(size_t)b * P + p0 + j];
    __syncthreads();
    const float* fp = f + ((size_t)b * NC + tid) * P + p0;
    float acc[NI];
    #pragma unroll
    for (int i = 0; i < NI; ++i) acc[i] = 0.0f;
    for (int pp = 0; pp < PT; pp += 4) {
        float4 v = *reinterpret_cast<const float4*>(fp + pp);
        uint2 mw = *reinterpret_cast<const uint2*>(lm + pp);
        const unsigned int m01 = mw.x;  // pixel pp in low 16 bits, pp+1 in high
        const unsigned int m23 = mw.y;  // pixel pp+2 low, pp+3 high
        #pragma unroll
        for (int i = 0; i < NI; ++i) {
            float a0 = (float)((m01 >> i) & 1u);
            float a1 = (float)((m01 >> (16 + i)) & 1u);
            float a2 = (float)((m23 >> i) & 1u);
            float a3 = (float)((m23 >> (16 + i)) & 1u);
            float t = a0 * v.x;
            t = fmaf(a1, v.y, t);
            t = fmaf(a2, v.z, t);
            t = fmaf(a3, v.w, t);
            acc[i] += t;
        }
    }
    float* sb = ssum + ((size_t)b * NI) * NC;
    #pragma unroll
    for (int i = 0; i < NI; ++i) atomicAdd(&sb[i * NC + tid], acc[i]);
}

// ---------------------------------------------------------------------------
// Kernel 3: finalize. out[b][i][c] = mean over 3 levels of
// (cnt>0 ? ssum/cnt : feat[b][c][argmax_idx]).
// ---------------------------------------------------------------------------
__global__ void final_kernel(const float* __restrict__ f0,
                             const float* __restrict__ f1,
                             const float* __restrict__ f2,
                             const int* __restrict__ cnt,
                             const unsigned long long* __restrict__ argm,
                             const float* __restrict__ ssum,
                             float* __restrict__ out) {
    const int bi = blockIdx.x;       // b*NI + i
    const int c = threadIdx.x;
    const int b = bi >> 4;
    const float* fl[3] = { f0, f1, f2 };
    const int Ps[3] = { 16384, 4096, 1024 };
    float r = 0.0f;
    #pragma unroll
    for (int l = 0; l < 3; ++l) {
        int cn = cnt[l * NB * NI + bi];
        float v;
        if (cn > 0) {
            v = ssum[((size_t)l * NB * NI + bi) * NC + c] / (float)cn;
        } else {
            unsigned int p = 0xFFFFFFFFu -
                (unsigned int)(argm[l * NB * NI + bi] & 0xFFFFFFFFull);
            v = fl[l][((size_t)b * NC + c) * Ps[l] + p];
        }
        r += v;
    }
    out[(size_t)bi * NC + c] = r * (1.0f / 3.0f);
}

extern "C" void kernel_launch(void* const* d_in, const int* in_sizes, int n_in,
                              void* d_out, int out_size, void* d_ws, size_t ws_size,
                              hipStream_t stream) {
    const float* f0  = (const float*)d_in[0];   // [8,256,128,128]
    const float* f1  = (const float*)d_in[1];   // [8,256,64,64]
    const float* f2  = (const float*)d_in[2];   // [8,256,32,32]
    const float* scr = (const float*)d_in[3];   // [8,16,512,512]
    float* out = (float*)d_out;                 // [8,16,256]
    char* ws = (char*)d_ws;
    if (ws_size < WS_NEED) return;  // visible failure rather than corruption

    uint16_t* m0 = (uint16_t*)(ws + OFF_M0);
    uint16_t* m1 = (uint16_t*)(ws + OFF_M1);
    uint16_t* m2 = (uint16_t*)(ws + OFF_M2);
    int* cnt = (int*)(ws + OFF_CNT);
    unsigned long long* argm = (unsigned long long*)(ws + OFF_ARG);
    float* ssum = (float*)(ws + OFF_SSUM);

    // zero accumulators (cnt, argmax keys, ssum) every call
    hipMemsetAsync(ws + OFF_CNT, 0, WS_NEED - OFF_CNT, stream);

    // masks + cnt + argmax per level
    mask_kernel<128, 4><<<dim3(64, NB), 256, 0, stream>>>(scr, m0, cnt + 0 * NB * NI, argm + 0 * NB * NI);
    mask_kernel<64,  8><<<dim3(16, NB), 256, 0, stream>>>(scr, m1, cnt + 1 * NB * NI, argm + 1 * NB * NI);
    mask_kernel<32, 16><<<dim3(4,  NB), 256, 0, stream>>>(scr, m2, cnt + 2 * NB * NI, argm + 2 * NB * NI);

    // masked channel sums per level
    ssum_kernel<16384, 256><<<dim3(64, NB), 256, 0, stream>>>(f0, m0, ssum + (size_t)0 * NB * NI * NC);
    ssum_kernel<4096,  128><<<dim3(32, NB), 256, 0, stream>>>(f1, m1, ssum + (size_t)1 * NB * NI * NC);
    ssum_kernel<1024,   64><<<dim3(16, NB), 256, 0, stream>>>(f2, m2, ssum + (size_t)2 * NB * NI * NC);

    // combine
    final_kernel<<<NB * NI, NC, 0, stream>>>(f0, f1, f2, cnt, argm, ssum, out);
}

// Round 2
// 209.476 us; speedup vs baseline: 1.4967x; 1.4967x over previous
//
#include <hip/hip_runtime.h>
#include <stdint.h>

#define NB 8
#define NI 16
#define NC 256
#define SH 512

// workspace layout (bytes)
static const size_t OFF_M0   = 0;                                  // u16 mask words, level0: 8*16384*2
static const size_t OFF_M1   = OFF_M0 + (size_t)NB * 16384 * 2;    // 262144
static const size_t OFF_M2   = OFF_M1 + (size_t)NB * 4096 * 2;     // 327680
static const size_t OFF_CNT  = OFF_M2 + (size_t)NB * 1024 * 2;     // 344064  int[3][8][16]
static const size_t OFF_ARG  = OFF_CNT + (size_t)3 * NB * NI * 4;  // 345600  u64[3][8][16]
static const size_t OFF_SSUM = OFF_ARG + (size_t)3 * NB * NI * 8;  // 348672  f32[3][8][16][256]
static const size_t WS_NEED  = OFF_SSUM + (size_t)3 * NB * NI * NC * 4; // 741888

// ---------------------------------------------------------------------------
// Kernel 1: per level, per pixel: sr for all 16 instances (exact 2x2 average),
// pack 16 mask bits -> ws, ballot-count cnt, wave-reduced argmax key -> atomicMax.
// key = (float_bits(sr) << 32) | (0xFFFFFFFF - pix)  => max value, first index.
// (sr >= 0 always: scribbles are uniform[0,1).)
// ---------------------------------------------------------------------------
template<int W, int S>
__global__ void mask_kernel(const float* __restrict__ scr,
                            uint16_t* __restrict__ mask,
                            int* __restrict__ cnt,
                            unsigned long long* __restrict__ argm) {
    const int P = W * W;
    const int pix = blockIdx.x * 256 + threadIdx.x;
    const int b = blockIdx.y;
    const int y = pix / W;
    const int x = pix - y * W;
    const int r0 = S * y + (S / 2 - 1);
    const int c0 = S * x + (S / 2 - 1);
    const int lane = threadIdx.x & 63;
    const float* sb = scr + (size_t)b * NI * SH * SH + (size_t)r0 * SH + c0;
    unsigned int mword = 0;
    for (int i = 0; i < NI; ++i) {
        const float* sp = sb + (size_t)i * SH * SH;
        float s4 = (sp[0] + sp[1]) + (sp[SH] + sp[SH + 1]);
        float sr = 0.25f * s4;
        bool bit = sr > 0.5f;
        mword |= bit ? (1u << i) : 0u;
        unsigned long long bal = __ballot(bit);
        unsigned long long key = (((unsigned long long)__float_as_uint(sr)) << 32)
                               | (unsigned long long)(0xFFFFFFFFu - (unsigned int)pix);
        #pragma unroll
        for (int off = 32; off > 0; off >>= 1) {
            unsigned long long o = __shfl_down(key, (unsigned)off, 64);
            key = (o > key) ? o : key;
        }
        if (lane == 0) {
            atomicAdd(&cnt[b * NI + i], (int)__popcll(bal));
            atomicMax(&argm[b * NI + i], key);
        }
    }
    mask[(size_t)b * P + pix] = (uint16_t)mword;
}

// ---------------------------------------------------------------------------
// Kernel 2 (rewritten): masked channel sums, COALESCED.
// One block (256 threads, 4 waves) owns one (b,c) feature row per level.
// Lanes span contiguous pixels: thread t handles float4 at pixel j*1024+4t
// (256 threads x 16 B = 4 KB contiguous per step), masks read as uint2
// (8 B/lane, coalesced). 16 register accumulators per lane; 64-lane shuffle
// reduce + cross-wave LDS combine; direct store (no atomics, no zeroing).
// All 3 levels fused in one kernel.
// ---------------------------------------------------------------------------
__device__ __forceinline__ float4 ld4(const float* p) {
    return *reinterpret_cast<const float4*>(p);
}

template<int P>
__device__ __forceinline__ void level_accum(const float* __restrict__ f,
                                            const uint16_t* __restrict__ m,
                                            float* __restrict__ ssum_bc, // + i*NC
                                            int b, int c, int tid,
                                            float* __restrict__ red) {
    const float* fp = f + (size_t)(b * NC + c) * P;
    const uint16_t* mp = m + (size_t)b * P;
    float acc[NI];
    #pragma unroll
    for (int i = 0; i < NI; ++i) acc[i] = 0.0f;
    #pragma unroll 2
    for (int j = 0; j < P / 1024; ++j) {
        const int idx = j * 1024 + tid * 4;
        float4 v = ld4(fp + idx);
        uint2 mw = *reinterpret_cast<const uint2*>(mp + idx);
        const unsigned int m01 = mw.x;  // pixel idx low 16, idx+1 high 16
        const unsigned int m23 = mw.y;  // pixel idx+2 low,  idx+3 high
        #pragma unroll
        for (int i = 0; i < NI; ++i) {
            float a0 = (float)((m01 >> i) & 1u);
            float a1 = (float)((m01 >> (16 + i)) & 1u);
            float a2 = (float)((m23 >> i) & 1u);
            float a3 = (float)((m23 >> (16 + i)) & 1u);
            float t = a0 * v.x;
            t = fmaf(a1, v.y, t);
            t = fmaf(a2, v.z, t);
            t = fmaf(a3, v.w, t);
            acc[i] += t;
        }
    }
    // 64-lane shuffle reduction per instance
    #pragma unroll
    for (int i = 0; i < NI; ++i) {
        float v = acc[i];
        #pragma unroll
        for (int off = 32; off > 0; off >>= 1)
            v += __shfl_down(v, off, 64);
        acc[i] = v;
    }
    const int wave = tid >> 6;
    const int lane = tid & 63;
    if (lane == 0) {
        #pragma unroll
        for (int i = 0; i < NI; ++i) red[i * 4 + wave] = acc[i];
    }
    __syncthreads();
    if (tid < NI) {
        float s = (red[tid * 4 + 0] + red[tid * 4 + 1])
                + (red[tid * 4 + 2] + red[tid * 4 + 3]);
        ssum_bc[tid * NC] = s;
    }
    __syncthreads();  // red reused by next level
}

__global__ __launch_bounds__(256) void ssum_all(const float* __restrict__ f0,
                                                const float* __restrict__ f1,
                                                const float* __restrict__ f2,
                                                const uint16_t* __restrict__ m0,
                                                const uint16_t* __restrict__ m1,
                                                const uint16_t* __restrict__ m2,
                                                float* __restrict__ ssum) {
    __shared__ float red[NI * 4];
    const int c = blockIdx.x;
    const int b = blockIdx.y;
    const int tid = threadIdx.x;
    level_accum<16384>(f0, m0, ssum + (size_t)(0 * NB + b) * NI * NC + c, b, c, tid, red);
    level_accum<4096>( f1, m1, ssum + (size_t)(1 * NB + b) * NI * NC + c, b, c, tid, red);
    level_accum<1024>( f2, m2, ssum + (size_t)(2 * NB + b) * NI * NC + c, b, c, tid, red);
}

// ---------------------------------------------------------------------------
// Kernel 3: finalize. out[b][i][c] = mean over 3 levels of
// (cnt>0 ? ssum/cnt : feat[b][c][argmax_idx]).
// ---------------------------------------------------------------------------
__global__ void final_kernel(const float* __restrict__ f0,
                             const float* __restrict__ f1,
                             const float* __restrict__ f2,
                             const int* __restrict__ cnt,
                             const unsigned long long* __restrict__ argm,
                             const float* __restrict__ ssum,
                             float* __restrict__ out) {
    const int bi = blockIdx.x;       // b*NI + i
    const int c = threadIdx.x;
    const int b = bi >> 4;
    const float* fl[3] = { f0, f1, f2 };
    const int Ps[3] = { 16384, 4096, 1024 };
    float r = 0.0f;
    #pragma unroll
    for (int l = 0; l < 3; ++l) {
        int cn = cnt[l * NB * NI + bi];
        float v;
        if (cn > 0) {
            v = ssum[((size_t)l * NB * NI + bi) * NC + c] / (float)cn;
        } else {
            unsigned int p = 0xFFFFFFFFu -
                (unsigned int)(argm[l * NB * NI + bi] & 0xFFFFFFFFull);
            v = fl[l][((size_t)b * NC + c) * Ps[l] + p];
        }
        r += v;
    }
    out[(size_t)bi * NC + c] = r * (1.0f / 3.0f);
}

extern "C" void kernel_launch(void* const* d_in, const int* in_sizes, int n_in,
                              void* d_out, int out_size, void* d_ws, size_t ws_size,
                              hipStream_t stream) {
    const float* f0  = (const float*)d_in[0];   // [8,256,128,128]
    const float* f1  = (const float*)d_in[1];   // [8,256,64,64]
    const float* f2  = (const float*)d_in[2];   // [8,256,32,32]
    const float* scr = (const float*)d_in[3];   // [8,16,512,512]
    float* out = (float*)d_out;                 // [8,16,256]
    char* ws = (char*)d_ws;
    if (ws_size < WS_NEED) return;  // visible failure rather than corruption

    uint16_t* m0 = (uint16_t*)(ws + OFF_M0);
    uint16_t* m1 = (uint16_t*)(ws + OFF_M1);
    uint16_t* m2 = (uint16_t*)(ws + OFF_M2);
    int* cnt = (int*)(ws + OFF_CNT);
    unsigned long long* argm = (unsigned long long*)(ws + OFF_ARG);
    float* ssum = (float*)(ws + OFF_SSUM);

    // zero accumulators (cnt, argmax keys) every call; ssum is fully overwritten
    hipMemsetAsync(ws + OFF_CNT, 0, OFF_SSUM - OFF_CNT, stream);

    // masks + cnt + argmax per level
    mask_kernel<128, 4><<<dim3(64, NB), 256, 0, stream>>>(scr, m0, cnt + 0 * NB * NI, argm + 0 * NB * NI);
    mask_kernel<64,  8><<<dim3(16, NB), 256, 0, stream>>>(scr, m1, cnt + 1 * NB * NI, argm + 1 * NB * NI);
    mask_kernel<32, 16><<<dim3(4,  NB), 256, 0, stream>>>(scr, m2, cnt + 2 * NB * NI, argm + 2 * NB * NI);

    // masked channel sums, all levels fused, coalesced
    ssum_all<<<dim3(NC, NB), 256, 0, stream>>>(f0, f1, f2, m0, m1, m2, ssum);

    // combine
    final_kernel<<<NB * NI, NC, 0, stream>>>(f0, f1, f2, cnt, argm, ssum, out);
}

// Round 3
// 70.801 us; speedup vs baseline: 4.4281x; 2.9587x over previous
//
#include <hip/hip_runtime.h>
#include <stdint.h>

#define NB 8
#define NI 16
#define NC 256
#define SH 512

typedef __bf16 bf16x8 __attribute__((ext_vector_type(8)));
typedef float f32x4 __attribute__((ext_vector_type(4)));
typedef uint32_t u32x4 __attribute__((ext_vector_type(4)));

// workspace layout (bytes)
static const size_t OFF_M0   = 0;                                  // u16 mask words, level0
static const size_t OFF_M1   = OFF_M0 + (size_t)NB * 16384 * 2;    // 262144
static const size_t OFF_M2   = OFF_M1 + (size_t)NB * 4096 * 2;     // 327680
static const size_t OFF_CNT  = OFF_M2 + (size_t)NB * 1024 * 2;     // 344064  int[3][8][16]
static const size_t OFF_ARG  = OFF_CNT + (size_t)3 * NB * NI * 4;  // 345600  u64[3][8][16]
static const size_t OFF_SSUM = OFF_ARG + (size_t)3 * NB * NI * 8;  // 348672  f32[3][8][16][256]
static const size_t WS_NEED  = OFF_SSUM + (size_t)3 * NB * NI * NC * 4; // 741888

__device__ __forceinline__ float4 ld4(const float* p) {
    return *reinterpret_cast<const float4*>(p);
}

// f32 pair -> packed bf16x2 word, round-nearest-even (no NaN handling; inputs finite)
__device__ __forceinline__ uint32_t bf16pk(float lo, float hi) {
    uint32_t u0 = __float_as_uint(lo), u1 = __float_as_uint(hi);
    uint32_t h0 = (u0 + 0x7FFFu + ((u0 >> 16) & 1u)) >> 16;
    uint32_t h1 = (u1 + 0x7FFFu + ((u1 >> 16) & 1u)) >> 16;
    return h0 | (h1 << 16);
}

// ---------------------------------------------------------------------------
// Mask kernel (fused 3 levels): per pixel compute sr for 16 instances (exact
// 2x2 average), pack 16 mask bits -> ws. cnt via ballot-popcount -> block LDS
// reduce -> 1 global atomic per (block, i). Argmax path only taken when the
// whole wave has zero foreground for instance i (any foreground wave proves
// cnt>0, making argm unused) -- so atomicMax contention is ~zero in practice.
// ---------------------------------------------------------------------------
template<int W, int S>
__device__ __forceinline__ void mask_level(const float* __restrict__ scr,
                                           uint16_t* __restrict__ mask,
                                           unsigned long long* __restrict__ argm,
                                           int b, int bx, int tid, int* lcnt) {
    const int P = W * W;
    const int pix = bx * 256 + tid;
    const int y = pix / W;
    const int x = pix - y * W;
    const int r0 = S * y + (S / 2 - 1);
    const int c0 = S * x + (S / 2 - 1);
    const int lane = tid & 63;
    const float* sb = scr + (size_t)b * NI * SH * SH + (size_t)r0 * SH;
    unsigned int mword = 0;
    for (int i = 0; i < NI; ++i) {
        const float* sp = sb + (size_t)i * SH * SH;
        float s4;
        if constexpr (S == 4) {
            // c0-1 = 4x -> 16B-aligned float4 covering cols 4x+1, 4x+2 in .y/.z
            float4 q0 = ld4(sp + (c0 - 1));
            float4 q1 = ld4(sp + SH + (c0 - 1));
            s4 = (q0.y + q0.z) + (q1.y + q1.z);
        } else {
            s4 = (sp[c0] + sp[c0 + 1]) + (sp[SH + c0] + sp[SH + c0 + 1]);
        }
        float sr = 0.25f * s4;
        bool bit = sr > 0.5f;
        mword |= bit ? (1u << i) : 0u;
        unsigned long long bal = __ballot(bit);
        if (lane == 0) atomicAdd(&lcnt[i], (int)__popcll(bal));
        if (bal == 0ull) {  // rare: whole wave empty -> contribute to argmax
            unsigned int srb = __float_as_uint(sr);  // sr >= 0 -> bits monotone
            unsigned int mx = srb;
            #pragma unroll
            for (int off = 1; off < 64; off <<= 1) {
                unsigned int o = __shfl_xor(mx, off, 64);
                mx = (o > mx) ? o : mx;
            }
            unsigned long long win = __ballot(srb == mx);
            if (lane == 0) {
                int wl = __ffsll(win) - 1;  // lowest lane = first (smallest) pix
                unsigned int wpix = (unsigned int)(bx * 256 + (tid & ~63) + wl);
                unsigned long long key = (((unsigned long long)mx) << 32)
                                       | (unsigned long long)(0xFFFFFFFFu - wpix);
                atomicMax(&argm[b * NI + i], key);
            }
        }
    }
    mask[(size_t)b * P + pix] = (uint16_t)mword;
}

__global__ __launch_bounds__(256) void mask_all(const float* __restrict__ scr,
                                                uint16_t* __restrict__ m0,
                                                uint16_t* __restrict__ m1,
                                                uint16_t* __restrict__ m2,
                                                int* __restrict__ cnt,
                                                unsigned long long* __restrict__ argm) {
    __shared__ int lcnt[NI];
    const int tid = threadIdx.x;
    const int b = blockIdx.y;
    const int bx = blockIdx.x;
    if (tid < NI) lcnt[tid] = 0;
    __syncthreads();
    int lvl;
    if (bx < 64) {
        mask_level<128, 4>(scr, m0, argm + 0 * NB * NI, b, bx, tid, lcnt);
        lvl = 0;
    } else if (bx < 80) {
        mask_level<64, 8>(scr, m1, argm + 1 * NB * NI, b, bx - 64, tid, lcnt);
        lvl = 1;
    } else {
        mask_level<32, 16>(scr, m2, argm + 2 * NB * NI, b, bx - 80, tid, lcnt);
        lvl = 2;
    }
    __syncthreads();
    if (tid < NI) {
        int v = lcnt[tid];
        if (v) atomicAdd(&cnt[lvl * NB * NI + b * NI + tid], v);
    }
}

// ---------------------------------------------------------------------------
// ssum via MFMA: ssum[b,i,c] = sum_p mask[b,i,p] * feat[b,c,p], a 16xP times
// Px256 GEMM per (b, level) on mfma_f32_16x16x32_bf16.
// Block = 256 thr = 4 waves; wave w covers channels w*64..w*64+63 (4 n-tiles),
// block covers a 256-pixel k-chunk. A-fragment: lane l = instance (l&15), k
// group (l>>4)*8; built from mask words: ((word >> i) & 0x10001) * 0x3F80
// = two bf16 {0,1.0} per u32. B-fragment: lane l = channel c0+(l&15), same k
// group -> 2 contiguous float4 per row; lane quartets read 128B contiguous.
// C/D layout (m89): row i = (l>>4)*4 + reg, col c = l&15. Partial outputs
// atomicAdd'd into ws (zeroed by memset).
// ---------------------------------------------------------------------------
template<int P>
__device__ __forceinline__ void ssum_level(const float* __restrict__ f,
                                           const uint16_t* __restrict__ m,
                                           float* __restrict__ ssum_l,
                                           int b, int chunk, int tid) {
    const int wave = tid >> 6;
    const int lane = tid & 63;
    const int kg = lane >> 4;   // k-subgroup 0..3
    const int cl = lane & 15;   // channel-within-tile (B/D) AND instance row (A)
    const int c0 = wave * 64;
    const int kb = chunk * 256;
    const uint16_t* mp = m + (size_t)b * P + kb + kg * 8;
    const float* fp0 = f + ((size_t)b * NC + c0 + cl) * P + kb + kg * 8;
    f32x4 acc0 = {0.f, 0.f, 0.f, 0.f};
    f32x4 acc1 = {0.f, 0.f, 0.f, 0.f};
    f32x4 acc2 = {0.f, 0.f, 0.f, 0.f};
    f32x4 acc3 = {0.f, 0.f, 0.f, 0.f};
    for (int ks = 0; ks < 8; ++ks) {
        const uint4 wA = *reinterpret_cast<const uint4*>(mp + ks * 32);
        u32x4 au;
        au.x = ((wA.x >> cl) & 0x10001u) * 0x3F80u;
        au.y = ((wA.y >> cl) & 0x10001u) * 0x3F80u;
        au.z = ((wA.z >> cl) & 0x10001u) * 0x3F80u;
        au.w = ((wA.w >> cl) & 0x10001u) * 0x3F80u;
        const bf16x8 av = __builtin_bit_cast(bf16x8, au);
        const float* fk = fp0 + ks * 32;
        #pragma unroll
        for (int nt = 0; nt < 4; ++nt) {
            const float* fr = fk + (size_t)nt * 16 * P;
            float4 v0 = ld4(fr);
            float4 v1 = ld4(fr + 4);
            u32x4 bu;
            bu.x = bf16pk(v0.x, v0.y);
            bu.y = bf16pk(v0.z, v0.w);
            bu.z = bf16pk(v1.x, v1.y);
            bu.w = bf16pk(v1.z, v1.w);
            const bf16x8 bv = __builtin_bit_cast(bf16x8, bu);
            if (nt == 0) acc0 = __builtin_amdgcn_mfma_f32_16x16x32_bf16(av, bv, acc0, 0, 0, 0);
            if (nt == 1) acc1 = __builtin_amdgcn_mfma_f32_16x16x32_bf16(av, bv, acc1, 0, 0, 0);
            if (nt == 2) acc2 = __builtin_amdgcn_mfma_f32_16x16x32_bf16(av, bv, acc2, 0, 0, 0);
            if (nt == 3) acc3 = __builtin_amdgcn_mfma_f32_16x16x32_bf16(av, bv, acc3, 0, 0, 0);
        }
    }
    float* sb = ssum_l + (size_t)b * NI * NC;
    #pragma unroll
    for (int nt = 0; nt < 4; ++nt) {
        const f32x4 ac = (nt == 0) ? acc0 : (nt == 1) ? acc1 : (nt == 2) ? acc2 : acc3;
        const int c = c0 + nt * 16 + cl;
        #pragma unroll
        for (int r = 0; r < 4; ++r)
            atomicAdd(&sb[(kg * 4 + r) * NC + c], ac[r]);
    }
}

__global__ __launch_bounds__(256) void ssum_all(const float* __restrict__ f0,
                                                const float* __restrict__ f1,
                                                const float* __restrict__ f2,
                                                const uint16_t* __restrict__ m0,
                                                const uint16_t* __restrict__ m1,
                                                const uint16_t* __restrict__ m2,
                                                float* __restrict__ ssum) {
    const int tid = threadIdx.x;
    const int b = blockIdx.y;
    const int bx = blockIdx.x;
    if (bx < 64) {
        ssum_level<16384>(f0, m0, ssum + (size_t)0 * NB * NI * NC, b, bx, tid);
    } else if (bx < 80) {
        ssum_level<4096>(f1, m1, ssum + (size_t)1 * NB * NI * NC, b, bx - 64, tid);
    } else {
        ssum_level<1024>(f2, m2, ssum + (size_t)2 * NB * NI * NC, b, bx - 80, tid);
    }
}

// ---------------------------------------------------------------------------
// Finalize. out[b][i][c] = mean over 3 levels of
// (cnt>0 ? ssum/cnt : feat[b][c][argmax_idx]).
// ---------------------------------------------------------------------------
__global__ void final_kernel(const float* __restrict__ f0,
                             const float* __restrict__ f1,
                             const float* __restrict__ f2,
                             const int* __restrict__ cnt,
                             const unsigned long long* __restrict__ argm,
                             const float* __restrict__ ssum,
                             float* __restrict__ out) {
    const int bi = blockIdx.x;       // b*NI + i
    const int c = threadIdx.x;
    const int b = bi >> 4;
    const float* fl[3] = { f0, f1, f2 };
    const int Ps[3] = { 16384, 4096, 1024 };
    float r = 0.0f;
    #pragma unroll
    for (int l = 0; l < 3; ++l) {
        int cn = cnt[l * NB * NI + bi];
        float v;
        if (cn > 0) {
            v = ssum[((size_t)l * NB * NI + bi) * NC + c] / (float)cn;
        } else {
            unsigned int p = 0xFFFFFFFFu -
                (unsigned int)(argm[l * NB * NI + bi] & 0xFFFFFFFFull);
            v = fl[l][((size_t)b * NC + c) * Ps[l] + p];
        }
        r += v;
    }
    out[(size_t)bi * NC + c] = r * (1.0f / 3.0f);
}

extern "C" void kernel_launch(void* const* d_in, const int* in_sizes, int n_in,
                              void* d_out, int out_size, void* d_ws, size_t ws_size,
                              hipStream_t stream) {
    const float* f0  = (const float*)d_in[0];   // [8,256,128,128]
    const float* f1  = (const float*)d_in[1];   // [8,256,64,64]
    const float* f2  = (const float*)d_in[2];   // [8,256,32,32]
    const float* scr = (const float*)d_in[3];   // [8,16,512,512]
    float* out = (float*)d_out;                 // [8,16,256]
    char* ws = (char*)d_ws;
    if (ws_size < WS_NEED) return;  // visible failure rather than corruption

    uint16_t* m0 = (uint16_t*)(ws + OFF_M0);
    uint16_t* m1 = (uint16_t*)(ws + OFF_M1);
    uint16_t* m2 = (uint16_t*)(ws + OFF_M2);
    int* cnt = (int*)(ws + OFF_CNT);
    unsigned long long* argm = (unsigned long long*)(ws + OFF_ARG);
    float* ssum = (float*)(ws + OFF_SSUM);

    // zero cnt, argm, ssum (all are accumulated into via atomics)
    hipMemsetAsync(ws + OFF_CNT, 0, WS_NEED - OFF_CNT, stream);

    // masks + cnt + argmax, all levels fused: 64 + 16 + 4 chunk-blocks per b
    mask_all<<<dim3(84, NB), 256, 0, stream>>>(scr, m0, m1, m2, cnt, argm);

    // masked channel sums via MFMA, all levels fused
    ssum_all<<<dim3(84, NB), 256, 0, stream>>>(f0, f1, f2, m0, m1, m2, ssum);

    // combine
    final_kernel<<<NB * NI, NC, 0, stream>>>(f0, f1, f2, cnt, argm, ssum, out);
}

// Round 4
// 65.131 us; speedup vs baseline: 4.8136x; 1.0871x over previous
//
#include <hip/hip_runtime.h>
#include <stdint.h>

#define NB 8
#define NI 16
#define NC 256
#define SH 512
#define NCH 84   // chunks per batch: 64 (L0) + 16 (L1) + 4 (L2)

typedef __bf16 bf16x8 __attribute__((ext_vector_type(8)));
typedef float f32x4 __attribute__((ext_vector_type(4)));
typedef uint32_t u32x4 __attribute__((ext_vector_type(4)));

// ws layout (bytes) — every slot is written unconditionally every call,
// so NO zero-init / memset is needed anywhere.
static const size_t OFF_SSP = 0;                                    // f32 [NB][NCH][NI][NC] partial sums
static const size_t OFF_CNT = OFF_SSP + (size_t)NB * NCH * NI * NC * 4;  // int [NB][NCH][NI]
static const size_t OFF_KEY = OFF_CNT + (size_t)NB * NCH * NI * 4;       // u64 [NB][NCH][NI]
static const size_t WS_NEED = OFF_KEY + (size_t)NB * NCH * NI * 8;       // ~11.1 MB

__device__ __forceinline__ float4 ld4(const float* p) {
    return *reinterpret_cast<const float4*>(p);
}

// ---------------------------------------------------------------------------
// Fused per-chunk kernel. Block = 256 thr = 4 waves; owns one 256-pixel chunk
// of one (b, level).
// Phase A: compute sr for 256 pixels x 16 instances (exact 2x2 average of the
//   scribble; bilinear at integer scale s with half-pixel centers == 0.5/0.5
//   weights), threshold (0.25*s4 > 0.5 <=> s4 > 2), pack 16 bits/pixel into
//   LDS. cnt via ballot-popcount -> LDS -> per-chunk slot (no global atomics).
//   Argmax key only computed when a whole wave is empty for instance i (if any
//   wave anywhere has a foreground bit, cnt>0 and the key path is dead).
//   key = (bits(sr)<<32) | (0xFFFFFFFF - pix): max => max sr, first index.
//   (sr >= 0 since scribbles are uniform[0,1) -> float bits monotone.)
// Phase B: ssum[i,c] = sum_p mask[i,p]*feat[c,p] via mfma_f32_16x16x32_bf16.
//   Wave w covers channels w*64..w*64+63 (4 n-tiles); k = the 256 chunk pixels
//   (8 k-steps). A-frag from LDS mask words: ((word>>i)&0x10001)*0x3F80 = two
//   bf16 {0,1.0}. B-frag: plain __bf16 casts -> compiler emits
//   v_cvt_pk_bf16_f32 (RNE, 1 inst / 2 floats). Each feature byte read once.
//   C/D layout (m89): row = (lane>>4)*4 + reg = instance, col = lane&15 = ch.
//   Partial [16][256] tile stored to this chunk's private slot.
// ---------------------------------------------------------------------------
template<int W, int S, int P>
__device__ __forceinline__ void do_chunk(const float* __restrict__ f,
                                         const float* __restrict__ scr,
                                         float* __restrict__ ssp,
                                         int* __restrict__ cntp,
                                         unsigned long long* __restrict__ keyp,
                                         int b, int chunk, int slot, int tid,
                                         uint16_t* __restrict__ lmask,
                                         int* __restrict__ lcnt,
                                         unsigned long long* __restrict__ lkey) {
    // ---- phase A ----
    const int pix = chunk * 256 + tid;
    const int y = pix / W;
    const int x = pix - y * W;
    const int r0 = S * y + (S / 2 - 1);
    const int c0s = S * x + (S / 2 - 1);
    const int lane = tid & 63;
    const float* sb = scr + (size_t)b * NI * SH * SH + (size_t)r0 * SH;
    unsigned int mword = 0;
    for (int i = 0; i < NI; ++i) {
        const float* sp = sb + (size_t)i * SH * SH;
        float s4;
        if constexpr (S == 4) {
            // c0s-1 = 4x -> 16B-aligned float4; cols 4x+1, 4x+2 are .y/.z
            float4 q0 = ld4(sp + (c0s - 1));
            float4 q1 = ld4(sp + SH + (c0s - 1));
            s4 = (q0.y + q0.z) + (q1.y + q1.z);
        } else {
            s4 = (sp[c0s] + sp[c0s + 1]) + (sp[SH + c0s] + sp[SH + c0s + 1]);
        }
        bool bit = s4 > 2.0f;                 // == (0.25*s4 > 0.5)
        mword |= bit ? (1u << i) : 0u;
        unsigned long long bal = __ballot(bit);
        if (lane == 0) atomicAdd(&lcnt[i], (int)__popcll(bal));
        if (bal == 0ull) {                    // whole wave empty -> argmax path
            unsigned int srb = __float_as_uint(0.25f * s4);
            unsigned int mx = srb;
            #pragma unroll
            for (int off = 1; off < 64; off <<= 1) {
                unsigned int o = __shfl_xor(mx, off, 64);
                mx = (o > mx) ? o : mx;
            }
            unsigned long long win = __ballot(srb == mx);
            if (lane == 0) {
                int wl = __ffsll((unsigned long long)win) - 1;  // first = smallest pix
                unsigned int wpix = (unsigned int)(chunk * 256 + (tid & ~63) + wl);
                unsigned long long key = (((unsigned long long)mx) << 32)
                                       | (unsigned long long)(0xFFFFFFFFu - wpix);
                atomicMax(&lkey[i], key);
            }
        }
    }
    lmask[tid] = (uint16_t)mword;
    __syncthreads();
    if (tid < NI) {
        cntp[slot * NI + tid] = lcnt[tid];
        keyp[slot * NI + tid] = lkey[tid];
    }

    // ---- phase B ----
    const int wave = tid >> 6;
    const int kg = lane >> 4;   // k-subgroup 0..3
    const int cl = lane & 15;   // channel-within-tile (B/D) AND instance row (A)
    const int c0 = wave * 64;
    const int kb = chunk * 256;
    const uint16_t* lmp = lmask + kg * 8;
    const float* fp0 = f + ((size_t)b * NC + c0 + cl) * P + kb + kg * 8;
    f32x4 acc0 = {0.f, 0.f, 0.f, 0.f};
    f32x4 acc1 = {0.f, 0.f, 0.f, 0.f};
    f32x4 acc2 = {0.f, 0.f, 0.f, 0.f};
    f32x4 acc3 = {0.f, 0.f, 0.f, 0.f};
    #pragma unroll
    for (int ks = 0; ks < 8; ++ks) {
        const uint4 wA = *reinterpret_cast<const uint4*>(lmp + ks * 32);
        u32x4 au;
        au.x = ((wA.x >> cl) & 0x10001u) * 0x3F80u;
        au.y = ((wA.y >> cl) & 0x10001u) * 0x3F80u;
        au.z = ((wA.z >> cl) & 0x10001u) * 0x3F80u;
        au.w = ((wA.w >> cl) & 0x10001u) * 0x3F80u;
        const bf16x8 av = __builtin_bit_cast(bf16x8, au);
        const float* fk = fp0 + ks * 32;
        #pragma unroll
        for (int nt = 0; nt < 4; ++nt) {
            const float* fr = fk + (size_t)(nt * 16) * P;
            float4 v0 = ld4(fr);
            float4 v1 = ld4(fr + 4);
            bf16x8 bv;
            bv[0] = (__bf16)v0.x; bv[1] = (__bf16)v0.y;
            bv[2] = (__bf16)v0.z; bv[3] = (__bf16)v0.w;
            bv[4] = (__bf16)v1.x; bv[5] = (__bf16)v1.y;
            bv[6] = (__bf16)v1.z; bv[7] = (__bf16)v1.w;
            if (nt == 0) acc0 = __builtin_amdgcn_mfma_f32_16x16x32_bf16(av, bv, acc0, 0, 0, 0);
            if (nt == 1) acc1 = __builtin_amdgcn_mfma_f32_16x16x32_bf16(av, bv, acc1, 0, 0, 0);
            if (nt == 2) acc2 = __builtin_amdgcn_mfma_f32_16x16x32_bf16(av, bv, acc2, 0, 0, 0);
            if (nt == 3) acc3 = __builtin_amdgcn_mfma_f32_16x16x32_bf16(av, bv, acc3, 0, 0, 0);
        }
    }
    float* sb2 = ssp + (size_t)slot * (NI * NC);
    #pragma unroll
    for (int nt = 0; nt < 4; ++nt) {
        const f32x4 ac = (nt == 0) ? acc0 : (nt == 1) ? acc1 : (nt == 2) ? acc2 : acc3;
        const int c = c0 + nt * 16 + cl;
        #pragma unroll
        for (int r = 0; r < 4; ++r)
            sb2[(kg * 4 + r) * NC + c] = ac[r];
    }
}

__global__ __launch_bounds__(256) void fused_kernel(const float* __restrict__ f0,
                                                    const float* __restrict__ f1,
                                                    const float* __restrict__ f2,
                                                    const float* __restrict__ scr,
                                                    float* __restrict__ ssp,
                                                    int* __restrict__ cntp,
                                                    unsigned long long* __restrict__ keyp) {
    __shared__ __align__(16) uint16_t lmask[256];
    __shared__ int lcnt[NI];
    __shared__ unsigned long long lkey[NI];
    const int tid = threadIdx.x;
    const int b = blockIdx.y;
    const int bx = blockIdx.x;
    if (tid < NI) { lcnt[tid] = 0; lkey[tid] = 0ull; }
    __syncthreads();
    const int slot = b * NCH + bx;
    if (bx < 64) {
        do_chunk<128, 4, 16384>(f0, scr, ssp, cntp, keyp, b, bx, slot, tid, lmask, lcnt, lkey);
    } else if (bx < 80) {
        do_chunk<64, 8, 4096>(f1, scr, ssp, cntp, keyp, b, bx - 64, slot, tid, lmask, lcnt, lkey);
    } else {
        do_chunk<32, 16, 1024>(f2, scr, ssp, cntp, keyp, b, bx - 80, slot, tid, lmask, lcnt, lkey);
    }
}

// ---------------------------------------------------------------------------
// Finalize: per (b,i), sum the per-chunk cnt and ssum partials per level;
// out = mean over levels of (cnt>0 ? ssum/cnt : feat[argmax]).
// ---------------------------------------------------------------------------
__global__ __launch_bounds__(256) void final_kernel(const float* __restrict__ f0,
                                                    const float* __restrict__ f1,
                                                    const float* __restrict__ f2,
                                                    const int* __restrict__ cntp,
                                                    const unsigned long long* __restrict__ keyp,
                                                    const float* __restrict__ ssp,
                                                    float* __restrict__ out) {
    __shared__ int scnt[3];
    __shared__ unsigned long long skey[3];
    const int bi = blockIdx.x;       // b*NI + i
    const int b = bi >> 4;
    const int i = bi & 15;
    const int tid = threadIdx.x;
    const int CH[3] = {64, 16, 4};
    const int O[3] = {0, 64, 80};
    if (tid < 64) {
        #pragma unroll
        for (int l = 0; l < 3; ++l) {
            int v = 0;
            unsigned long long k = 0ull;
            if (tid < CH[l]) {
                const int slot = b * NCH + O[l] + tid;
                v = cntp[slot * NI + i];
                k = keyp[slot * NI + i];
            }
            #pragma unroll
            for (int off = 32; off > 0; off >>= 1) {
                v += __shfl_down(v, off, 64);
                unsigned long long ko = __shfl_down(k, off, 64);
                k = (ko > k) ? ko : k;
            }
            if (tid == 0) { scnt[l] = v; skey[l] = k; }
        }
    }
    __syncthreads();
    const float* fl[3] = {f0, f1, f2};
    const int Ps[3] = {16384, 4096, 1024};
    const int c = tid;
    float r = 0.f;
    #pragma unroll
    for (int l = 0; l < 3; ++l) {
        const int cn = scnt[l];
        float v;
        if (cn > 0) {
            float s = 0.f;
            for (int j = 0; j < CH[l]; ++j)
                s += ssp[((size_t)(b * NCH + O[l] + j) * NI + i) * NC + c];
            v = s / (float)cn;
        } else {
            unsigned int p = 0xFFFFFFFFu - (unsigned int)(skey[l] & 0xFFFFFFFFull);
            v = fl[l][((size_t)b * NC + c) * Ps[l] + p];
        }
        r += v;
    }
    out[(size_t)bi * NC + c] = r * (1.f / 3.f);
}

extern "C" void kernel_launch(void* const* d_in, const int* in_sizes, int n_in,
                              void* d_out, int out_size, void* d_ws, size_t ws_size,
                              hipStream_t stream) {
    const float* f0  = (const float*)d_in[0];   // [8,256,128,128]
    const float* f1  = (const float*)d_in[1];   // [8,256,64,64]
    const float* f2  = (const float*)d_in[2];   // [8,256,32,32]
    const float* scr = (const float*)d_in[3];   // [8,16,512,512]
    float* out = (float*)d_out;                 // [8,16,256]
    char* ws = (char*)d_ws;
    if (ws_size < WS_NEED) return;  // visible failure rather than corruption

    float* ssp = (float*)(ws + OFF_SSP);
    int* cntp = (int*)(ws + OFF_CNT);
    unsigned long long* keyp = (unsigned long long*)(ws + OFF_KEY);

    // no memset: every ws slot below is written unconditionally each call
    fused_kernel<<<dim3(NCH, NB), 256, 0, stream>>>(f0, f1, f2, scr, ssp, cntp, keyp);
    final_kernel<<<NB * NI, NC, 0, stream>>>(f0, f1, f2, cntp, keyp, ssp, out);
}